// Round 1
// baseline (51.453 us; speedup 1.0000x reference)
//
#include <hip/hip_runtime.h>

#define B_ 4
#define T_ 4096
#define D_ 2048
#define W_ 4
#define D4_ (D_ / 4)          // 512 float4 per row
#define TCHUNK 64
#define NTC (T_ / TCHUNK)     // 64 chunks

__device__ __forceinline__ float silu_f(float v) {
    return v / (1.0f + __expf(-v));
}

__global__ __launch_bounds__(256) void conv_silu_kernel(
    const float* __restrict__ x, const float* __restrict__ w,
    float* __restrict__ out)
{
    int gid = blockIdx.x * blockDim.x + threadIdx.x;   // 0 .. B*NTC*D4-1
    int d4   = gid % D4_;                // consecutive threads -> consecutive d4 (coalesced)
    int rest = gid / D4_;
    int tc   = rest % NTC;
    int b    = rest / NTC;

    const float4* x4 = (const float4*)x;
    const float4* w4 = (const float4*)w;
    float4*       y4 = (float4*)out;

    // depthwise taps for these 4 channels (tap W-1 hits the current token)
    float4 w0 = w4[0 * D4_ + d4];
    float4 w1 = w4[1 * D4_ + d4];
    float4 w2 = w4[2 * D4_ + d4];
    float4 w3 = w4[3 * D4_ + d4];

    int   t0   = tc * TCHUNK;
    long  base = (long)b * T_ * D4_;     // in float4 units

    float4 zero = make_float4(0.f, 0.f, 0.f, 0.f);
    // sliding window of the 3 previous tokens (zero-padded at t<0)
    float4 xm3 = (t0 >= 3) ? x4[base + (long)(t0 - 3) * D4_ + d4] : zero;
    float4 xm2 = (t0 >= 2) ? x4[base + (long)(t0 - 2) * D4_ + d4] : zero;
    float4 xm1 = (t0 >= 1) ? x4[base + (long)(t0 - 1) * D4_ + d4] : zero;

    #pragma unroll 4
    for (int t = t0; t < t0 + TCHUNK; ++t) {
        float4 x0 = x4[base + (long)t * D4_ + d4];
        float4 y;
        y.x = w0.x * xm3.x + w1.x * xm2.x + w2.x * xm1.x + w3.x * x0.x;
        y.y = w0.y * xm3.y + w1.y * xm2.y + w2.y * xm1.y + w3.y * x0.y;
        y.z = w0.z * xm3.z + w1.z * xm2.z + w2.z * xm1.z + w3.z * x0.z;
        y.w = w0.w * xm3.w + w1.w * xm2.w + w2.w * xm1.w + w3.w * x0.w;
        y.x = silu_f(y.x);
        y.y = silu_f(y.y);
        y.z = silu_f(y.z);
        y.w = silu_f(y.w);
        y4[base + (long)t * D4_ + d4] = y;
        xm3 = xm2; xm2 = xm1; xm1 = x0;
    }
}

// final_state = x[:, T-W:, :]  -> out[B*T*D + b*W*D + k*D + d]
__global__ __launch_bounds__(256) void final_state_kernel(
    const float* __restrict__ x, float* __restrict__ out)
{
    int gid = blockIdx.x * blockDim.x + threadIdx.x;   // 0 .. B*W*D4-1 (8192)
    int d4   = gid % D4_;
    int rest = gid / D4_;                // 0..15
    int k    = rest % W_;
    int b    = rest / W_;
    const float4* x4 = (const float4*)x;
    float4* o4 = (float4*)out + ((long)B_ * T_ * D_) / 4;
    o4[gid] = x4[(long)b * T_ * D4_ + (long)(T_ - W_ + k) * D4_ + d4];
}

extern "C" void kernel_launch(void* const* d_in, const int* in_sizes, int n_in,
                              void* d_out, int out_size, void* d_ws, size_t ws_size,
                              hipStream_t stream) {
    const float* x = (const float*)d_in[0];
    const float* w = (const float*)d_in[1];
    float* out = (float*)d_out;

    int total_main = B_ * NTC * D4_;          // 131072 threads
    conv_silu_kernel<<<total_main / 256, 256, 0, stream>>>(x, w, out);

    int total_fs = B_ * W_ * D4_;             // 8192 threads
    final_state_kernel<<<total_fs / 256, 256, 0, stream>>>(x, out);
}